// Round 3
// baseline (612.010 us; speedup 1.0000x reference)
//
#include <hip/hip_runtime.h>
#include <hip/hip_fp16.h>

// ComposeTransform: out = compose([t1,t2,t3]) with dense displacement fields.
//   r   = t3 + interp(t2, grid + t3)
//   out = r  + interp(t1, grid + r)
// R5 -> R6:
//  - REVERT nontemporal LOADS everywhere. R5 evidence: conv(t2) regressed
//    ~115 -> ~160us and K3 likely slowed; nt-bit on reads bypasses L2/LLC
//    allocation (hurts streaming conv; hurts K3 shift reads of just-written
//    L2-resident data). NT kept ONLY on K3's final store (never re-read).
//  - conv: 2 tiles/block (3840 blocks), shared LDS hoisted & reused with a
//    barrier, to amortize dispatch ramp on this short kernel.
//  - keep: conv(t1) fused under pass-A warp (proven: +22us instead of
//    +110us standalone), explicit 16B row-pair gathers, XCD swizzle.
// R5 counters: fused 197us @2.0TB/s (24.5%), VALU 12.3%, occ 72%,
// FETCH 224MB / WRITE 153MB (matches byte model).

#define BB 2
#define DD 128
#define HH 160
#define WW 192

// warp kernel tiling: block = 256 threads x 2 voxels = 4d x 2h x 64w tile
#define WT_TILES 3   // 192/64
#define HT_TILES 80  // 160/2
#define DT_TILES 32  // 128/4
#define NBLOCKS (WT_TILES * HT_TILES * DT_TILES * BB)  // 15360
#define PER_XCD (NBLOCKS / 8)                          // 1920

#define NVOX ((long)BB * DD * HH * WW)      // 7,864,320 voxels
#define CONV_TILES ((int)(NVOX / 1024))     // 7680 tiles of 1024 voxels
#define CONV_BLOCKS (CONV_TILES / 2)        // 3840 blocks x 2 tiles
#define VOLH_BYTES ((size_t)NVOX * 8)       // 62,914,560 per f16 volume

typedef unsigned int uint4v __attribute__((ext_vector_type(4)));
typedef uint4v uint4v_a8 __attribute__((aligned(8)));   // 8B-aligned 16B load
typedef float floatx2 __attribute__((ext_vector_type(2)));
typedef float floatx4 __attribute__((ext_vector_type(4)));

static __device__ __forceinline__ float3 cvt_h3(unsigned w0, unsigned w1) {
    float x = __half2float(__ushort_as_half((unsigned short)(w0 & 0xffffu)));
    float y = __half2float(__ushort_as_half((unsigned short)(w0 >> 16)));
    float z = __half2float(__ushort_as_half((unsigned short)(w1 & 0xffffu)));
    return make_float3(x, y, z);
}

// ---------------- conversion role: f32 [.,3] -> f16 padded [.,4] ------------
// One tile = 256 threads x 1024 voxels: 768 coalesced float4 loads -> LDS ->
// 4x coalesced uint2 stores per thread. Plain loads (keep L2 allocation).
static __device__ __forceinline__ void conv_tile(
    const floatx4* __restrict__ src, uint2* __restrict__ dst, unsigned tile,
    floatx4* lds4)
{
    const float* lds = (const float*)lds4;

    long base = (long)tile * 1024;        // first voxel of this tile
    const floatx4* s4 = src + (long)tile * 768;
    int tid = threadIdx.x;

#pragma unroll
    for (int j = 0; j < 3; ++j)
        lds4[tid + 256 * j] = s4[tid + 256 * j];
    __syncthreads();

#pragma unroll
    for (int j = 0; j < 4; ++j) {
        int v = tid + 256 * j;
        float x = lds[3 * v], y = lds[3 * v + 1], z = lds[3 * v + 2];
        uint2 q;
        q.x = (unsigned)__half_as_ushort(__float2half_rn(x)) |
              ((unsigned)__half_as_ushort(__float2half_rn(y)) << 16);
        q.y = (unsigned)__half_as_ushort(__float2half_rn(z));
        dst[base + v] = q;
    }
}

__global__ __launch_bounds__(256) void conv_f16_kernel(
    const floatx4* __restrict__ src, uint2* __restrict__ dst)
{
    __shared__ floatx4 lds4[768];         // 12 KB, reused across both tiles
    conv_tile(src, dst, blockIdx.x, lds4);
    __syncthreads();                      // LDS reads done before overwrite
    conv_tile(src, dst, blockIdx.x + CONV_BLOCKS, lds4);
}

// ---------------- warp role: out = shift + interp(vol, grid + shift) --------
static __device__ __forceinline__ void interp_one(
    const uint2* __restrict__ baseq, int d, int h, int w,
    float sx, float sy, float sz, float& ox, float& oy, float& oz)
{
    float lx = fminf(fmaxf((float)d + sx, 0.f), (float)(DD - 1));
    float ly = fminf(fmaxf((float)h + sy, 0.f), (float)(HH - 1));
    float lz = fminf(fmaxf((float)w + sz, 0.f), (float)(WW - 1));

    float fx = floorf(lx), fy = floorf(ly), fz = floorf(lz);
    int x0 = (int)fx, y0 = (int)fy, z0 = (int)fz;
    int x1 = min(x0 + 1, DD - 1);
    int y1 = min(y0 + 1, HH - 1);

    int  z0m = min(z0, WW - 2);
    bool zhi = (z0 == WW - 1);

    float wx0 = (float)x1 - lx;
    float wy0 = (float)y1 - ly;
    float wz0 = (float)(min(z0 + 1, WW - 1)) - lz;
    float wx1 = 1.f - wx0;
    float wy1 = 1.f - wy0;
    float wz1 = 1.f - wz0;

    // issue all 4 row-pair 16B loads (independent) before use
    const uint4v_a8* p00 = (const uint4v_a8*)(baseq + (((long)x0 * HH + y0) * WW + z0m));
    const uint4v_a8* p01 = (const uint4v_a8*)(baseq + (((long)x0 * HH + y1) * WW + z0m));
    const uint4v_a8* p10 = (const uint4v_a8*)(baseq + (((long)x1 * HH + y0) * WW + z0m));
    const uint4v_a8* p11 = (const uint4v_a8*)(baseq + (((long)x1 * HH + y1) * WW + z0m));
    uint4v q00 = *p00;
    uint4v q01 = *p01;
    uint4v q10 = *p10;
    uint4v q11 = *p11;

    float ax = 0.f, ay = 0.f, az = 0.f;
#define ROWPAIR(Q, WXY) do {                                                \
        float3 vlo = cvt_h3(Q.x, Q.y);                                      \
        float3 vhi = cvt_h3(Q.z, Q.w);                                      \
        float3 v0  = zhi ? vhi : vlo;                                       \
        float wt_ = (WXY);                                                  \
        ax = fmaf(wt_, fmaf(wz0, v0.x, wz1 * vhi.x), ax);                   \
        ay = fmaf(wt_, fmaf(wz0, v0.y, wz1 * vhi.y), ay);                   \
        az = fmaf(wt_, fmaf(wz0, v0.z, wz1 * vhi.z), az);                   \
    } while (0)
    ROWPAIR(q00, wx0 * wy0);
    ROWPAIR(q01, wx0 * wy1);
    ROWPAIR(q10, wx1 * wy0);
    ROWPAIR(q11, wx1 * wy1);
#undef ROWPAIR

    ox = sx + ax;
    oy = sy + ay;
    oz = sz + az;
}

template <bool NTSTORE>
static __device__ __forceinline__ void warp_body(
    const uint2* __restrict__ vol4,  // sampled field, f16 padded [B,D,H,W,4]
    const float* shift,              // current transform (may alias out)
    float* out, unsigned bid)
{
    // XCD swizzle: contiguous spatial slab per XCD for L2 halo reuse.
    unsigned sbid = (bid & 7u) * PER_XCD + (bid >> 3);

    unsigned wt  = sbid % WT_TILES;  unsigned t0 = sbid / WT_TILES;
    unsigned ht  = t0 % HT_TILES;    unsigned t1 = t0 / HT_TILES;
    unsigned dt  = t1 % DT_TILES;    unsigned b  = t1 / DT_TILES;

    unsigned tid = threadIdx.x;
    int w = wt * 64 + 2 * (tid & 31);        // even; handles w, w+1
    int h = ht * 2  + ((tid >> 5) & 1);
    int d = dt * 4  + (tid >> 6);

    const long nvb = (long)DD * HH * WW;
    long idx = (long)b * nvb + (((long)d * HH + h) * WW + w);

    // 2 voxels' shifts: 6 contiguous floats, 8B-aligned; plain loads so
    // just-written L2-resident data (K3: shift==out from K2) stays cheap.
    const floatx2* sp2 = (const floatx2*)(shift + idx * 3);
    floatx2 sa = sp2[0];
    floatx2 sb = sp2[1];
    floatx2 sc = sp2[2];

    const uint2* baseq = vol4 + (long)b * nvb;

    float o0x, o0y, o0z, o1x, o1y, o1z;
    interp_one(baseq, d, h, w,     sa.x, sa.y, sb.x, o0x, o0y, o0z);
    interp_one(baseq, d, h, w + 1, sb.y, sc.x, sc.y, o1x, o1y, o1z);

    floatx2* op2 = (floatx2*)(out + idx * 3);
    floatx2 r0; r0.x = o0x; r0.y = o0y;
    floatx2 r1; r1.x = o0z; r1.y = o1x;
    floatx2 r2; r2.x = o1y; r2.y = o1z;
    if (NTSTORE) {
        __builtin_nontemporal_store(r0, &op2[0]);
        __builtin_nontemporal_store(r1, &op2[1]);
        __builtin_nontemporal_store(r2, &op2[2]);
    } else {
        op2[0] = r0;
        op2[1] = r1;
        op2[2] = r2;
    }
}

__global__ __launch_bounds__(256) void warp_add_h_kernel(
    const uint2* __restrict__ vol4, const float* shift, float* out)
{
    warp_body<false>(vol4, shift, out, blockIdx.x);
}

__global__ __launch_bounds__(256) void warp_add_h_nt_kernel(
    const uint2* __restrict__ vol4, const float* shift, float* out)
{
    warp_body<true>(vol4, shift, out, blockIdx.x);
}

// Pass A warp + conv(t1) overlapped: first CONV_TILES blocks convert t1
// into volB (pure BW, one tile each), the rest run the request-bound warp
// of volA. CONV_TILES = 7680 is a multiple of 8, so the warp role's XCD
// swizzle (bid & 7) keeps the same XCD alignment as a standalone launch.
__global__ __launch_bounds__(256) void fused_warp_conv_kernel(
    const uint2* __restrict__ vol4, const float* shift, float* out,
    const floatx4* __restrict__ csrc, uint2* __restrict__ cdst)
{
    __shared__ floatx4 lds4[768];         // 12 KB (warp role: unused)
    unsigned bid = blockIdx.x;
    if (bid < (unsigned)CONV_TILES) {
        conv_tile(csrc, cdst, bid, lds4);
    } else {
        warp_body<false>(vol4, shift, out, bid - CONV_TILES);
    }
}

extern "C" void kernel_launch(void* const* d_in, const int* in_sizes, int n_in,
                              void* d_out, int out_size, void* d_ws, size_t ws_size,
                              hipStream_t stream) {
    const float* t1 = (const float*)d_in[0];
    const float* t2 = (const float*)d_in[1];
    const float* t3 = (const float*)d_in[2];
    float* out  = (float*)d_out;

    uint2* volA = (uint2*)d_ws;

    if (ws_size >= 2 * VOLH_BYTES) {
        uint2* volB = (uint2*)((char*)d_ws + VOLH_BYTES);
        // K1: stage t2 as f16
        conv_f16_kernel<<<CONV_BLOCKS, 256, 0, stream>>>((const floatx4*)t2, volA);
        // K2: r = t3 + interp(t2, grid+t3) -> out, overlapped with conv(t1)->volB
        fused_warp_conv_kernel<<<CONV_TILES + NBLOCKS, 256, 0, stream>>>(
            volA, t3, out, (const floatx4*)t1, volB);
        // K3: out = r + interp(t1, grid+r), in-place, final write never re-read
        warp_add_h_nt_kernel<<<NBLOCKS, 256, 0, stream>>>(volB, out, out);
    } else {
        // Fallback: sequential flow with a single staged volume.
        conv_f16_kernel<<<CONV_BLOCKS, 256, 0, stream>>>((const floatx4*)t2, volA);
        warp_add_h_kernel<<<NBLOCKS, 256, 0, stream>>>(volA, t3, out);
        conv_f16_kernel<<<CONV_BLOCKS, 256, 0, stream>>>((const floatx4*)t1, volA);
        warp_add_h_nt_kernel<<<NBLOCKS, 256, 0, stream>>>(volA, out, out);
    }
}

// Round 4
// 552.955 us; speedup vs baseline: 1.1068x; 1.1068x over previous
//
#include <hip/hip_runtime.h>
#include <hip/hip_fp16.h>

// ComposeTransform: out = compose([t1,t2,t3]) with dense displacement fields.
//   r   = t3 + interp(t2, grid + t3)
//   out = r  + interp(t1, grid + r)
// R6 -> R7: per-kernel cherry-pick of measured-best configs.
//  - K1 conv(t2): PLAIN loads, 1 tile/block (R4: ~115us). NT loads cost
//    ~+30us standalone (R5); 2-tile/block cost ~+100us (R6).
//  - K2 fused warp+conv(t1): NT loads on conv src + shift (R5: 197us vs
//    R6 plain 223us) -- NT streams don't evict volA's gather lines in L2.
//  - K3 warp: PLAIN shift loads (streams hit just-written L2 data), NT
//    store of final output (never re-read).
// Accounting (OH~0): R4=115+175+115+175=580; R5=546 (NT hurt K1/K3 +59,
// fusion saved -93); R6=612 (2-tile conv ~214, fused w/o NT 223).

#define BB 2
#define DD 128
#define HH 160
#define WW 192

// warp kernel tiling: block = 256 threads x 2 voxels = 4d x 2h x 64w tile
#define WT_TILES 3   // 192/64
#define HT_TILES 80  // 160/2
#define DT_TILES 32  // 128/4
#define NBLOCKS (WT_TILES * HT_TILES * DT_TILES * BB)  // 15360
#define PER_XCD (NBLOCKS / 8)                          // 1920

#define NVOX ((long)BB * DD * HH * WW)      // 7,864,320 voxels
#define CONV_BLOCKS ((int)(NVOX / 1024))    // 7680, 1 tile (1024 vox) each
#define VOLH_BYTES ((size_t)NVOX * 8)       // 62,914,560 per f16 volume

typedef unsigned int uint4v __attribute__((ext_vector_type(4)));
typedef uint4v uint4v_a8 __attribute__((aligned(8)));   // 8B-aligned 16B load
typedef float floatx2 __attribute__((ext_vector_type(2)));
typedef float floatx4 __attribute__((ext_vector_type(4)));

static __device__ __forceinline__ float3 cvt_h3(unsigned w0, unsigned w1) {
    float x = __half2float(__ushort_as_half((unsigned short)(w0 & 0xffffu)));
    float y = __half2float(__ushort_as_half((unsigned short)(w0 >> 16)));
    float z = __half2float(__ushort_as_half((unsigned short)(w1 & 0xffffu)));
    return make_float3(x, y, z);
}

// ---------------- conversion role: f32 [.,3] -> f16 padded [.,4] ------------
// One tile = 256 threads x 1024 voxels: 768 coalesced float4 loads -> LDS ->
// 4x coalesced uint2 stores per thread.
template <bool NTLOAD>
static __device__ __forceinline__ void conv_body(
    const floatx4* __restrict__ src, uint2* __restrict__ dst, unsigned bid)
{
    __shared__ floatx4 lds4[768];         // 12 KB
    const float* lds = (const float*)lds4;

    long base = (long)bid * 1024;         // first voxel of this tile
    const floatx4* s4 = src + (long)bid * 768;
    int tid = threadIdx.x;

#pragma unroll
    for (int j = 0; j < 3; ++j) {
        if (NTLOAD)
            lds4[tid + 256 * j] = __builtin_nontemporal_load(&s4[tid + 256 * j]);
        else
            lds4[tid + 256 * j] = s4[tid + 256 * j];
    }
    __syncthreads();

#pragma unroll
    for (int j = 0; j < 4; ++j) {
        int v = tid + 256 * j;
        float x = lds[3 * v], y = lds[3 * v + 1], z = lds[3 * v + 2];
        uint2 q;
        q.x = (unsigned)__half_as_ushort(__float2half_rn(x)) |
              ((unsigned)__half_as_ushort(__float2half_rn(y)) << 16);
        q.y = (unsigned)__half_as_ushort(__float2half_rn(z));
        dst[base + v] = q;
    }
}

__global__ __launch_bounds__(256) void conv_f16_kernel(
    const floatx4* __restrict__ src, uint2* __restrict__ dst)
{
    conv_body<false>(src, dst, blockIdx.x);   // plain loads: R4-proven
}

// ---------------- warp role: out = shift + interp(vol, grid + shift) --------
static __device__ __forceinline__ void interp_one(
    const uint2* __restrict__ baseq, int d, int h, int w,
    float sx, float sy, float sz, float& ox, float& oy, float& oz)
{
    float lx = fminf(fmaxf((float)d + sx, 0.f), (float)(DD - 1));
    float ly = fminf(fmaxf((float)h + sy, 0.f), (float)(HH - 1));
    float lz = fminf(fmaxf((float)w + sz, 0.f), (float)(WW - 1));

    float fx = floorf(lx), fy = floorf(ly), fz = floorf(lz);
    int x0 = (int)fx, y0 = (int)fy, z0 = (int)fz;
    int x1 = min(x0 + 1, DD - 1);
    int y1 = min(y0 + 1, HH - 1);

    int  z0m = min(z0, WW - 2);
    bool zhi = (z0 == WW - 1);

    float wx0 = (float)x1 - lx;
    float wy0 = (float)y1 - ly;
    float wz0 = (float)(min(z0 + 1, WW - 1)) - lz;
    float wx1 = 1.f - wx0;
    float wy1 = 1.f - wy0;
    float wz1 = 1.f - wz0;

    // issue all 4 row-pair 16B loads (independent) before use
    const uint4v_a8* p00 = (const uint4v_a8*)(baseq + (((long)x0 * HH + y0) * WW + z0m));
    const uint4v_a8* p01 = (const uint4v_a8*)(baseq + (((long)x0 * HH + y1) * WW + z0m));
    const uint4v_a8* p10 = (const uint4v_a8*)(baseq + (((long)x1 * HH + y0) * WW + z0m));
    const uint4v_a8* p11 = (const uint4v_a8*)(baseq + (((long)x1 * HH + y1) * WW + z0m));
    uint4v q00 = *p00;
    uint4v q01 = *p01;
    uint4v q10 = *p10;
    uint4v q11 = *p11;

    float ax = 0.f, ay = 0.f, az = 0.f;
#define ROWPAIR(Q, WXY) do {                                                \
        float3 vlo = cvt_h3(Q.x, Q.y);                                      \
        float3 vhi = cvt_h3(Q.z, Q.w);                                      \
        float3 v0  = zhi ? vhi : vlo;                                       \
        float wt_ = (WXY);                                                  \
        ax = fmaf(wt_, fmaf(wz0, v0.x, wz1 * vhi.x), ax);                   \
        ay = fmaf(wt_, fmaf(wz0, v0.y, wz1 * vhi.y), ay);                   \
        az = fmaf(wt_, fmaf(wz0, v0.z, wz1 * vhi.z), az);                   \
    } while (0)
    ROWPAIR(q00, wx0 * wy0);
    ROWPAIR(q01, wx0 * wy1);
    ROWPAIR(q10, wx1 * wy0);
    ROWPAIR(q11, wx1 * wy1);
#undef ROWPAIR

    ox = sx + ax;
    oy = sy + ay;
    oz = sz + az;
}

template <bool NTLOAD, bool NTSTORE>
static __device__ __forceinline__ void warp_body(
    const uint2* __restrict__ vol4,  // sampled field, f16 padded [B,D,H,W,4]
    const float* shift,              // current transform (may alias out)
    float* out, unsigned bid)
{
    // XCD swizzle: contiguous spatial slab per XCD for L2 halo reuse.
    unsigned sbid = (bid & 7u) * PER_XCD + (bid >> 3);

    unsigned wt  = sbid % WT_TILES;  unsigned t0 = sbid / WT_TILES;
    unsigned ht  = t0 % HT_TILES;    unsigned t1 = t0 / HT_TILES;
    unsigned dt  = t1 % DT_TILES;    unsigned b  = t1 / DT_TILES;

    unsigned tid = threadIdx.x;
    int w = wt * 64 + 2 * (tid & 31);        // even; handles w, w+1
    int h = ht * 2  + ((tid >> 5) & 1);
    int d = dt * 4  + (tid >> 6);

    const long nvb = (long)DD * HH * WW;
    long idx = (long)b * nvb + (((long)d * HH + h) * WW + w);

    // 2 voxels' shifts: 6 contiguous floats, 8B-aligned.
    // NTLOAD only when a concurrent gather stream needs L2 protection (K2).
    const floatx2* sp2 = (const floatx2*)(shift + idx * 3);
    floatx2 sa, sb, sc;
    if (NTLOAD) {
        sa = __builtin_nontemporal_load(&sp2[0]);
        sb = __builtin_nontemporal_load(&sp2[1]);
        sc = __builtin_nontemporal_load(&sp2[2]);
    } else {
        sa = sp2[0];
        sb = sp2[1];
        sc = sp2[2];
    }

    const uint2* baseq = vol4 + (long)b * nvb;

    float o0x, o0y, o0z, o1x, o1y, o1z;
    interp_one(baseq, d, h, w,     sa.x, sa.y, sb.x, o0x, o0y, o0z);
    interp_one(baseq, d, h, w + 1, sb.y, sc.x, sc.y, o1x, o1y, o1z);

    floatx2* op2 = (floatx2*)(out + idx * 3);
    floatx2 r0; r0.x = o0x; r0.y = o0y;
    floatx2 r1; r1.x = o0z; r1.y = o1x;
    floatx2 r2; r2.x = o1y; r2.y = o1z;
    if (NTSTORE) {
        __builtin_nontemporal_store(r0, &op2[0]);
        __builtin_nontemporal_store(r1, &op2[1]);
        __builtin_nontemporal_store(r2, &op2[2]);
    } else {
        op2[0] = r0;
        op2[1] = r1;
        op2[2] = r2;
    }
}

__global__ __launch_bounds__(256) void warp_add_h_kernel(
    const uint2* __restrict__ vol4, const float* shift, float* out)
{
    warp_body<false, false>(vol4, shift, out, blockIdx.x);
}

// K3: plain shift loads (reads K2's just-written, L2-resident output),
// NT store of the final result (never re-read).
__global__ __launch_bounds__(256) void warp_add_h_nt_kernel(
    const uint2* __restrict__ vol4, const float* shift, float* out)
{
    warp_body<false, true>(vol4, shift, out, blockIdx.x);
}

// Pass A warp + conv(t1) overlapped: first CONV_BLOCKS blocks convert t1
// into volB (pure BW, NT loads), the rest run the request-bound warp of
// volA (NT shift loads). CONV_BLOCKS = 7680 is a multiple of 8, so the
// warp role's XCD swizzle (bid & 7) keeps standalone-launch alignment.
__global__ __launch_bounds__(256) void fused_warp_conv_kernel(
    const uint2* __restrict__ vol4, const float* shift, float* out,
    const floatx4* __restrict__ csrc, uint2* __restrict__ cdst)
{
    unsigned bid = blockIdx.x;
    if (bid < (unsigned)CONV_BLOCKS) {
        conv_body<true>(csrc, cdst, bid);
    } else {
        warp_body<true, false>(vol4, shift, out, bid - CONV_BLOCKS);
    }
}

extern "C" void kernel_launch(void* const* d_in, const int* in_sizes, int n_in,
                              void* d_out, int out_size, void* d_ws, size_t ws_size,
                              hipStream_t stream) {
    const float* t1 = (const float*)d_in[0];
    const float* t2 = (const float*)d_in[1];
    const float* t3 = (const float*)d_in[2];
    float* out  = (float*)d_out;

    uint2* volA = (uint2*)d_ws;

    if (ws_size >= 2 * VOLH_BYTES) {
        uint2* volB = (uint2*)((char*)d_ws + VOLH_BYTES);
        // K1: stage t2 as f16 (plain loads, 1 tile/block)
        conv_f16_kernel<<<CONV_BLOCKS, 256, 0, stream>>>((const floatx4*)t2, volA);
        // K2: r = t3 + interp(t2, grid+t3) -> out, overlapped with conv(t1)->volB
        fused_warp_conv_kernel<<<CONV_BLOCKS + NBLOCKS, 256, 0, stream>>>(
            volA, t3, out, (const floatx4*)t1, volB);
        // K3: out = r + interp(t1, grid+r), in-place, final write never re-read
        warp_add_h_nt_kernel<<<NBLOCKS, 256, 0, stream>>>(volB, out, out);
    } else {
        // Fallback: sequential flow with a single staged volume.
        conv_f16_kernel<<<CONV_BLOCKS, 256, 0, stream>>>((const floatx4*)t2, volA);
        warp_add_h_kernel<<<NBLOCKS, 256, 0, stream>>>(volA, t3, out);
        conv_f16_kernel<<<CONV_BLOCKS, 256, 0, stream>>>((const floatx4*)t1, volA);
        warp_add_h_nt_kernel<<<NBLOCKS, 256, 0, stream>>>(volA, out, out);
    }
}

// Round 5
// 552.888 us; speedup vs baseline: 1.1069x; 1.0001x over previous
//
#include <hip/hip_runtime.h>
#include <hip/hip_fp16.h>

// ComposeTransform: out = compose([t1,t2,t3]) with dense displacement fields.
//   r   = t3 + interp(t2, grid + t3)
//   out = r  + interp(t1, grid + r)
// R7 -> R8: single-variable isolation — K3 store goes back to PLAIN.
// Ledger (gaps~0, fused pinned by rocprof):
//   R4: conv 115 + warp 175 + conv 115 + warp 175 = 581 (plain everything)
//   R5: K1+K3=349 (both NT-load, K3 NT-store), fused 197
//   R6: K1+K3=389 (2-tile conv +34, K3 NT-store), fused-plain 223
//   R7: K1+K3=355 (plain loads, K3 NT-store),     fused-NT  198
// => NT loads standalone: neutral (349 vs 355). Fused NT loads: -26 (real).
// => K3 with NT store ~ 240 vs R4's plain-store warp 175. R4 FETCH shows
//    gather volume was LLC-cold even in R4 (181MB = shift 94 + volA 87),
//    so coldness doesn't explain it; suspect = NT store. This round tests it.

#define BB 2
#define DD 128
#define HH 160
#define WW 192

// warp kernel tiling: block = 256 threads x 2 voxels = 4d x 2h x 64w tile
#define WT_TILES 3   // 192/64
#define HT_TILES 80  // 160/2
#define DT_TILES 32  // 128/4
#define NBLOCKS (WT_TILES * HT_TILES * DT_TILES * BB)  // 15360
#define PER_XCD (NBLOCKS / 8)                          // 1920

#define NVOX ((long)BB * DD * HH * WW)      // 7,864,320 voxels
#define CONV_BLOCKS ((int)(NVOX / 1024))    // 7680, 1 tile (1024 vox) each
#define VOLH_BYTES ((size_t)NVOX * 8)       // 62,914,560 per f16 volume

typedef unsigned int uint4v __attribute__((ext_vector_type(4)));
typedef uint4v uint4v_a8 __attribute__((aligned(8)));   // 8B-aligned 16B load
typedef float floatx2 __attribute__((ext_vector_type(2)));
typedef float floatx4 __attribute__((ext_vector_type(4)));

static __device__ __forceinline__ float3 cvt_h3(unsigned w0, unsigned w1) {
    float x = __half2float(__ushort_as_half((unsigned short)(w0 & 0xffffu)));
    float y = __half2float(__ushort_as_half((unsigned short)(w0 >> 16)));
    float z = __half2float(__ushort_as_half((unsigned short)(w1 & 0xffffu)));
    return make_float3(x, y, z);
}

// ---------------- conversion role: f32 [.,3] -> f16 padded [.,4] ------------
// One tile = 256 threads x 1024 voxels: 768 coalesced float4 loads -> LDS ->
// 4x coalesced uint2 stores per thread.
template <bool NTLOAD>
static __device__ __forceinline__ void conv_body(
    const floatx4* __restrict__ src, uint2* __restrict__ dst, unsigned bid)
{
    __shared__ floatx4 lds4[768];         // 12 KB
    const float* lds = (const float*)lds4;

    long base = (long)bid * 1024;         // first voxel of this tile
    const floatx4* s4 = src + (long)bid * 768;
    int tid = threadIdx.x;

#pragma unroll
    for (int j = 0; j < 3; ++j) {
        if (NTLOAD)
            lds4[tid + 256 * j] = __builtin_nontemporal_load(&s4[tid + 256 * j]);
        else
            lds4[tid + 256 * j] = s4[tid + 256 * j];
    }
    __syncthreads();

#pragma unroll
    for (int j = 0; j < 4; ++j) {
        int v = tid + 256 * j;
        float x = lds[3 * v], y = lds[3 * v + 1], z = lds[3 * v + 2];
        uint2 q;
        q.x = (unsigned)__half_as_ushort(__float2half_rn(x)) |
              ((unsigned)__half_as_ushort(__float2half_rn(y)) << 16);
        q.y = (unsigned)__half_as_ushort(__float2half_rn(z));
        dst[base + v] = q;
    }
}

__global__ __launch_bounds__(256) void conv_f16_kernel(
    const floatx4* __restrict__ src, uint2* __restrict__ dst)
{
    conv_body<false>(src, dst, blockIdx.x);   // plain loads: R4-proven
}

// ---------------- warp role: out = shift + interp(vol, grid + shift) --------
static __device__ __forceinline__ void interp_one(
    const uint2* __restrict__ baseq, int d, int h, int w,
    float sx, float sy, float sz, float& ox, float& oy, float& oz)
{
    float lx = fminf(fmaxf((float)d + sx, 0.f), (float)(DD - 1));
    float ly = fminf(fmaxf((float)h + sy, 0.f), (float)(HH - 1));
    float lz = fminf(fmaxf((float)w + sz, 0.f), (float)(WW - 1));

    float fx = floorf(lx), fy = floorf(ly), fz = floorf(lz);
    int x0 = (int)fx, y0 = (int)fy, z0 = (int)fz;
    int x1 = min(x0 + 1, DD - 1);
    int y1 = min(y0 + 1, HH - 1);

    int  z0m = min(z0, WW - 2);
    bool zhi = (z0 == WW - 1);

    float wx0 = (float)x1 - lx;
    float wy0 = (float)y1 - ly;
    float wz0 = (float)(min(z0 + 1, WW - 1)) - lz;
    float wx1 = 1.f - wx0;
    float wy1 = 1.f - wy0;
    float wz1 = 1.f - wz0;

    // issue all 4 row-pair 16B loads (independent) before use
    const uint4v_a8* p00 = (const uint4v_a8*)(baseq + (((long)x0 * HH + y0) * WW + z0m));
    const uint4v_a8* p01 = (const uint4v_a8*)(baseq + (((long)x0 * HH + y1) * WW + z0m));
    const uint4v_a8* p10 = (const uint4v_a8*)(baseq + (((long)x1 * HH + y0) * WW + z0m));
    const uint4v_a8* p11 = (const uint4v_a8*)(baseq + (((long)x1 * HH + y1) * WW + z0m));
    uint4v q00 = *p00;
    uint4v q01 = *p01;
    uint4v q10 = *p10;
    uint4v q11 = *p11;

    float ax = 0.f, ay = 0.f, az = 0.f;
#define ROWPAIR(Q, WXY) do {                                                \
        float3 vlo = cvt_h3(Q.x, Q.y);                                      \
        float3 vhi = cvt_h3(Q.z, Q.w);                                      \
        float3 v0  = zhi ? vhi : vlo;                                       \
        float wt_ = (WXY);                                                  \
        ax = fmaf(wt_, fmaf(wz0, v0.x, wz1 * vhi.x), ax);                   \
        ay = fmaf(wt_, fmaf(wz0, v0.y, wz1 * vhi.y), ay);                   \
        az = fmaf(wt_, fmaf(wz0, v0.z, wz1 * vhi.z), az);                   \
    } while (0)
    ROWPAIR(q00, wx0 * wy0);
    ROWPAIR(q01, wx0 * wy1);
    ROWPAIR(q10, wx1 * wy0);
    ROWPAIR(q11, wx1 * wy1);
#undef ROWPAIR

    ox = sx + ax;
    oy = sy + ay;
    oz = sz + az;
}

template <bool NTLOAD>
static __device__ __forceinline__ void warp_body(
    const uint2* __restrict__ vol4,  // sampled field, f16 padded [B,D,H,W,4]
    const float* shift,              // current transform (may alias out)
    float* out, unsigned bid)
{
    // XCD swizzle: contiguous spatial slab per XCD for L2 halo reuse.
    unsigned sbid = (bid & 7u) * PER_XCD + (bid >> 3);

    unsigned wt  = sbid % WT_TILES;  unsigned t0 = sbid / WT_TILES;
    unsigned ht  = t0 % HT_TILES;    unsigned t1 = t0 / HT_TILES;
    unsigned dt  = t1 % DT_TILES;    unsigned b  = t1 / DT_TILES;

    unsigned tid = threadIdx.x;
    int w = wt * 64 + 2 * (tid & 31);        // even; handles w, w+1
    int h = ht * 2  + ((tid >> 5) & 1);
    int d = dt * 4  + (tid >> 6);

    const long nvb = (long)DD * HH * WW;
    long idx = (long)b * nvb + (((long)d * HH + h) * WW + w);

    // 2 voxels' shifts: 6 contiguous floats, 8B-aligned.
    // NTLOAD only in the fused kernel (protects volA gather lines in cache).
    const floatx2* sp2 = (const floatx2*)(shift + idx * 3);
    floatx2 sa, sb, sc;
    if (NTLOAD) {
        sa = __builtin_nontemporal_load(&sp2[0]);
        sb = __builtin_nontemporal_load(&sp2[1]);
        sc = __builtin_nontemporal_load(&sp2[2]);
    } else {
        sa = sp2[0];
        sb = sp2[1];
        sc = sp2[2];
    }

    const uint2* baseq = vol4 + (long)b * nvb;

    float o0x, o0y, o0z, o1x, o1y, o1z;
    interp_one(baseq, d, h, w,     sa.x, sa.y, sb.x, o0x, o0y, o0z);
    interp_one(baseq, d, h, w + 1, sb.y, sc.x, sc.y, o1x, o1y, o1z);

    floatx2* op2 = (floatx2*)(out + idx * 3);
    floatx2 r0; r0.x = o0x; r0.y = o0y;
    floatx2 r1; r1.x = o0z; r1.y = o1x;
    floatx2 r2; r2.x = o1y; r2.y = o1z;
    op2[0] = r0;   // plain stores: R8 isolates the R5-R7 NT-store suspect
    op2[1] = r1;
    op2[2] = r2;
}

__global__ __launch_bounds__(256) void warp_add_h_kernel(
    const uint2* __restrict__ vol4, const float* shift, float* out)
{
    warp_body<false>(vol4, shift, out, blockIdx.x);
}

// Pass A warp + conv(t1) overlapped: first CONV_BLOCKS blocks convert t1
// into volB (pure BW, NT loads), the rest run the request-bound warp of
// volA (NT shift loads). CONV_BLOCKS = 7680 is a multiple of 8, so the
// warp role's XCD swizzle (bid & 7) keeps standalone-launch alignment.
__global__ __launch_bounds__(256) void fused_warp_conv_kernel(
    const uint2* __restrict__ vol4, const float* shift, float* out,
    const floatx4* __restrict__ csrc, uint2* __restrict__ cdst)
{
    unsigned bid = blockIdx.x;
    if (bid < (unsigned)CONV_BLOCKS) {
        conv_body<true>(csrc, cdst, bid);
    } else {
        warp_body<true>(vol4, shift, out, bid - CONV_BLOCKS);
    }
}

extern "C" void kernel_launch(void* const* d_in, const int* in_sizes, int n_in,
                              void* d_out, int out_size, void* d_ws, size_t ws_size,
                              hipStream_t stream) {
    const float* t1 = (const float*)d_in[0];
    const float* t2 = (const float*)d_in[1];
    const float* t3 = (const float*)d_in[2];
    float* out  = (float*)d_out;

    uint2* volA = (uint2*)d_ws;

    if (ws_size >= 2 * VOLH_BYTES) {
        uint2* volB = (uint2*)((char*)d_ws + VOLH_BYTES);
        // K1: stage t2 as f16 (plain loads, 1 tile/block)
        conv_f16_kernel<<<CONV_BLOCKS, 256, 0, stream>>>((const floatx4*)t2, volA);
        // K2: r = t3 + interp(t2, grid+t3) -> out, overlapped with conv(t1)->volB
        fused_warp_conv_kernel<<<CONV_BLOCKS + NBLOCKS, 256, 0, stream>>>(
            volA, t3, out, (const floatx4*)t1, volB);
        // K3: out = r + interp(t1, grid+r), in-place, plain stores
        warp_add_h_kernel<<<NBLOCKS, 256, 0, stream>>>(volB, out, out);
    } else {
        // Fallback: sequential flow with a single staged volume.
        conv_f16_kernel<<<CONV_BLOCKS, 256, 0, stream>>>((const floatx4*)t2, volA);
        warp_add_h_kernel<<<NBLOCKS, 256, 0, stream>>>(volA, t3, out);
        conv_f16_kernel<<<CONV_BLOCKS, 256, 0, stream>>>((const floatx4*)t1, volA);
        warp_add_h_kernel<<<NBLOCKS, 256, 0, stream>>>(volA, out, out);
    }
}